// Round 1
// baseline (3306.508 us; speedup 1.0000x reference)
//
#include <hip/hip_runtime.h>

#define N_NODES 100000
#define E_EDGES 1600000
#define DIN 256
#define NH 4
#define DH 32
#define COUT 256
#define LN_EPS 1e-9f

// ---------------------------------------------------------------------------
// Transpose W (2,4,256,32) -> Wt[d][c], c = o*128 + h*32 + k  (256x256 f32)
// ---------------------------------------------------------------------------
__global__ __launch_bounds__(256) void wt_kernel(const float* __restrict__ W,
                                                 float* __restrict__ Wt) {
    int i = blockIdx.x * 256 + threadIdx.x;   // 65536 elements
    int d = i >> 8, c = i & 255;
    int o = c >> 7, h = (c >> 5) & 3, k = c & 31;
    Wt[i] = W[((o * NH + h) * DIN + d) * DH + k];
}

// ---------------------------------------------------------------------------
// GEMM: feat = relu(feat_in @ Wt + b), fused epilogues:
//   o==0 (self): LayerNorm -> out[:, 0:128];  att_s = leaky(dot(x, a_self))
//   o==1 (nei):  raw x -> feat_nei;           att_n = leaky(dot(x, a_neigh))
// Block: 256 threads = 16(tx: col groups of 16) x 16(ty: node pairs), 32 nodes.
// ---------------------------------------------------------------------------
__global__ __launch_bounds__(256) void gemm_kernel(
    const float* __restrict__ feat_in, const float* __restrict__ Wt,
    const float* __restrict__ b, const float* __restrict__ att,
    const float* __restrict__ scale, const float* __restrict__ offset,
    float* __restrict__ out, float* __restrict__ feat_nei,
    float* __restrict__ att_s, float* __restrict__ att_n)
{
    __shared__ float sA[32][36];    // 32 nodes x 32 k (pad 36 vs bank conflicts)
    __shared__ float sW[32][260];   // 32 k x 256 cols (pad 260)

    const int t  = threadIdx.x;
    const int tx = t & 15, ty = t >> 4;
    const int base = blockIdx.x * 32;
    const int c0 = tx * 16;     // 16 consecutive output cols
    const int m0 = ty * 2;      // 2 nodes

    float acc0[16], acc1[16];
#pragma unroll
    for (int j = 0; j < 16; ++j) { acc0[j] = 0.f; acc1[j] = 0.f; }

    const int sm = t >> 3, sj = t & 7;
    for (int kc = 0; kc < DIN; kc += 32) {
        // stage A tile: 32 nodes x 32 k
        *(float4*)&sA[sm][sj * 4] =
            *(const float4*)&feat_in[(base + sm) * DIN + kc + sj * 4];
        // stage W tile: 32 k x 256 c (one full row per wave iteration)
#pragma unroll
        for (int r = 0; r < 8; ++r) {
            int lin = r * 256 + t;
            int d = lin >> 6, q = lin & 63;
            *(float4*)&sW[d][q * 4] = *(const float4*)&Wt[(kc + d) * COUT + q * 4];
        }
        __syncthreads();
#pragma unroll
        for (int d4 = 0; d4 < 32; d4 += 4) {
            float4 a0 = *(const float4*)&sA[m0][d4];
            float4 a1 = *(const float4*)&sA[m0 + 1][d4];
            float a0v[4] = {a0.x, a0.y, a0.z, a0.w};
            float a1v[4] = {a1.x, a1.y, a1.z, a1.w};
#pragma unroll
            for (int j = 0; j < 4; ++j) {
                float wv[16];
                *(float4*)&wv[0]  = *(const float4*)&sW[d4 + j][c0];
                *(float4*)&wv[4]  = *(const float4*)&sW[d4 + j][c0 + 4];
                *(float4*)&wv[8]  = *(const float4*)&sW[d4 + j][c0 + 8];
                *(float4*)&wv[12] = *(const float4*)&sW[d4 + j][c0 + 12];
#pragma unroll
                for (int q = 0; q < 16; ++q) {
                    acc0[q] = fmaf(a0v[j], wv[q], acc0[q]);
                    acc1[q] = fmaf(a1v[j], wv[q], acc1[q]);
                }
            }
        }
        __syncthreads();
    }

    // ---- epilogue ----
    const int o = c0 >> 7;
    const int h = (c0 >> 5) & 3;
    const int kbase = c0 & 31;          // 0 or 16
    float bias[16], attw[16], sc[16], of[16];
#pragma unroll
    for (int j = 0; j < 16; j += 4) {
        *(float4*)&bias[j] = *(const float4*)&b[c0 + j];
        *(float4*)&sc[j]   = *(const float4*)&scale[c0 + j];
        *(float4*)&of[j]   = *(const float4*)&offset[c0 + j];
        *(float4*)&attw[j] = *(const float4*)&att[h * 64 + o * 32 + kbase + j];
    }

#pragma unroll
    for (int mm = 0; mm < 2; ++mm) {
        float* accp = mm ? acc1 : acc0;
        float x[16];
        float s1 = 0.f, s2 = 0.f, sa = 0.f;
#pragma unroll
        for (int j = 0; j < 16; ++j) {
            float v = fmaxf(accp[j] + bias[j], 0.f);
            x[j] = v;
            s1 += v; s2 += v * v; sa += v * attw[j];
        }
        // head = 32 cols = tx pair (lane^1 within wave)
        s1 += __shfl_xor(s1, 1);
        s2 += __shfl_xor(s2, 1);
        sa += __shfl_xor(sa, 1);
        float mean = s1 * (1.f / 32.f);
        float var  = s2 * (1.f / 32.f) - mean * mean;
        float rstd = rsqrtf(fmaxf(var, 0.f) + LN_EPS);
        float a_out = sa >= 0.f ? sa : 0.2f * sa;
        int n = base + m0 + mm;

        if (o == 0) {
#pragma unroll
            for (int j = 0; j < 16; ++j)
                x[j] = (x[j] - mean) * rstd * sc[j] + of[j];
#pragma unroll
            for (int j = 0; j < 16; j += 4)
                *(float4*)&out[n * COUT + c0 + j] = *(float4*)&x[j];
            if (kbase == 0) att_s[h * N_NODES + n] = a_out;
        } else {
#pragma unroll
            for (int j = 0; j < 16; j += 4)
                *(float4*)&feat_nei[n * 128 + (c0 - 128) + j] = *(float4*)&x[j];
            if (kbase == 0) att_n[h * N_NODES + n] = a_out;
        }
    }
}

// ---------------------------------------------------------------------------
// Edge scatter: one 32-lane group per edge; lane li handles 4 consecutive
// channels (h = li>>3).  out[row, 128:256] += w_h * feat_nei[col].
// ---------------------------------------------------------------------------
__global__ __launch_bounds__(256) void edge_kernel(
    const int* __restrict__ row, const int* __restrict__ col,
    const float* __restrict__ adj,
    const float* __restrict__ att_s, const float* __restrict__ att_n,
    const float* __restrict__ feat_nei, float* __restrict__ out)
{
    int tid = blockIdx.x * 256 + threadIdx.x;
    int e  = tid >> 5;
    int li = threadIdx.x & 31;
    int r = row[e], c = col[e];
    float av = adj[e];
    int h = li >> 3;
    float w = (att_s[h * N_NODES + r] + att_n[h * N_NODES + c]) * av;
    float4 f = *(const float4*)&feat_nei[c * 128 + li * 4];
    float* dst = out + r * COUT + 128 + li * 4;
    unsafeAtomicAdd(dst + 0, w * f.x);
    unsafeAtomicAdd(dst + 1, w * f.y);
    unsafeAtomicAdd(dst + 2, w * f.z);
    unsafeAtomicAdd(dst + 3, w * f.w);
}

// ---------------------------------------------------------------------------
// In-place LayerNorm of out[:, 128:256] per (n,h) group of 32.
// ---------------------------------------------------------------------------
__global__ __launch_bounds__(256) void ln_kernel(
    const float* __restrict__ scale, const float* __restrict__ offset,
    float* __restrict__ out)
{
    int idx = blockIdx.x * 256 + threadIdx.x;
    int g = idx >> 5;
    int k = idx & 31;
    int n = g >> 2, h = g & 3;
    float* p = out + n * COUT + 128 + h * DH;
    float x = p[k];
    float s1 = x, s2 = x * x;
#pragma unroll
    for (int off = 16; off; off >>= 1) {
        s1 += __shfl_xor(s1, off, 32);
        s2 += __shfl_xor(s2, off, 32);
    }
    float mean = s1 * (1.f / 32.f);
    float var  = s2 * (1.f / 32.f) - mean * mean;
    float rstd = rsqrtf(fmaxf(var, 0.f) + LN_EPS);
    int ci = 128 + h * DH + k;
    p[k] = (x - mean) * scale[ci] * rstd + offset[ci];
}

// ---------------------------------------------------------------------------
extern "C" void kernel_launch(void* const* d_in, const int* in_sizes, int n_in,
                              void* d_out, int out_size, void* d_ws, size_t ws_size,
                              hipStream_t stream)
{
    const float* feat_in = (const float*)d_in[0];
    const int*   row     = (const int*)d_in[1];
    const int*   col     = (const int*)d_in[2];
    const float* adj     = (const float*)d_in[3];
    const float* W       = (const float*)d_in[4];
    const float* b       = (const float*)d_in[5];
    const float* att     = (const float*)d_in[6];
    const float* scale   = (const float*)d_in[7];
    const float* offset  = (const float*)d_in[8];
    float* out = (float*)d_out;

    float* ws       = (float*)d_ws;
    float* Wt       = ws;                       // 65536 f32
    float* att_s    = Wt + 65536;               // 4*N f32
    float* att_n    = att_s + NH * N_NODES;     // 4*N f32
    float* feat_nei = att_n + NH * N_NODES;     // N*128 f32
    // total ws: ~54.7 MB

    hipMemsetAsync(d_out, 0, (size_t)out_size * sizeof(float), stream);
    wt_kernel<<<256, 256, 0, stream>>>(W, Wt);
    gemm_kernel<<<N_NODES / 32, 256, 0, stream>>>(feat_in, Wt, b, att, scale,
                                                  offset, out, feat_nei, att_s, att_n);
    edge_kernel<<<(E_EDGES * 32) / 256, 256, 0, stream>>>(row, col, adj, att_s,
                                                          att_n, feat_nei, out);
    ln_kernel<<<(N_NODES * NH * 32) / 256, 256, 0, stream>>>(scale, offset, out);
}

// Round 3
// 1154.450 us; speedup vs baseline: 2.8641x; 2.8641x over previous
//
#include <hip/hip_runtime.h>

#define N_NODES 100000
#define E_EDGES 1600000
#define DIN 256
#define NH 4
#define DH 32
#define COUT 256
#define LN_EPS 1e-9f

// ---------------------------------------------------------------------------
// Transpose W (2,4,256,32) -> Wt[d][c], c = o*128 + h*32 + k  (256x256 f32)
// ---------------------------------------------------------------------------
__global__ __launch_bounds__(256) void wt_kernel(const float* __restrict__ W,
                                                 float* __restrict__ Wt) {
    int i = blockIdx.x * 256 + threadIdx.x;   // 65536 elements
    int d = i >> 8, c = i & 255;
    int o = c >> 7, h = (c >> 5) & 3, k = c & 31;
    Wt[i] = W[((o * NH + h) * DIN + d) * DH + k];
}

// ---------------------------------------------------------------------------
// GEMM: feat = relu(feat_in @ Wt + b), fused epilogues:
//   o==0 (self): LayerNorm -> out[:, 0:128];  att_s = leaky(dot(x, a_self))
//   o==1 (nei):  raw x -> feat_nei;           att_n = leaky(dot(x, a_neigh))
// ---------------------------------------------------------------------------
__global__ __launch_bounds__(256) void gemm_kernel(
    const float* __restrict__ feat_in, const float* __restrict__ Wt,
    const float* __restrict__ b, const float* __restrict__ att,
    const float* __restrict__ scale, const float* __restrict__ offset,
    float* __restrict__ out, float* __restrict__ feat_nei,
    float* __restrict__ att_s, float* __restrict__ att_n)
{
    __shared__ float sA[32][36];
    __shared__ float sW[32][260];

    const int t  = threadIdx.x;
    const int tx = t & 15, ty = t >> 4;
    const int base = blockIdx.x * 32;
    const int c0 = tx * 16;
    const int m0 = ty * 2;

    float acc0[16], acc1[16];
#pragma unroll
    for (int j = 0; j < 16; ++j) { acc0[j] = 0.f; acc1[j] = 0.f; }

    const int sm = t >> 3, sj = t & 7;
    for (int kc = 0; kc < DIN; kc += 32) {
        *(float4*)&sA[sm][sj * 4] =
            *(const float4*)&feat_in[(base + sm) * DIN + kc + sj * 4];
#pragma unroll
        for (int r = 0; r < 8; ++r) {
            int lin = r * 256 + t;
            int d = lin >> 6, q = lin & 63;
            *(float4*)&sW[d][q * 4] = *(const float4*)&Wt[(kc + d) * COUT + q * 4];
        }
        __syncthreads();
#pragma unroll
        for (int d4 = 0; d4 < 32; d4 += 4) {
            float4 a0 = *(const float4*)&sA[m0][d4];
            float4 a1 = *(const float4*)&sA[m0 + 1][d4];
            float a0v[4] = {a0.x, a0.y, a0.z, a0.w};
            float a1v[4] = {a1.x, a1.y, a1.z, a1.w};
#pragma unroll
            for (int j = 0; j < 4; ++j) {
                float wv[16];
                *(float4*)&wv[0]  = *(const float4*)&sW[d4 + j][c0];
                *(float4*)&wv[4]  = *(const float4*)&sW[d4 + j][c0 + 4];
                *(float4*)&wv[8]  = *(const float4*)&sW[d4 + j][c0 + 8];
                *(float4*)&wv[12] = *(const float4*)&sW[d4 + j][c0 + 12];
#pragma unroll
                for (int q = 0; q < 16; ++q) {
                    acc0[q] = fmaf(a0v[j], wv[q], acc0[q]);
                    acc1[q] = fmaf(a1v[j], wv[q], acc1[q]);
                }
            }
        }
        __syncthreads();
    }

    const int o = c0 >> 7;
    const int h = (c0 >> 5) & 3;
    const int kbase = c0 & 31;
    float bias[16], attw[16], sc[16], of[16];
#pragma unroll
    for (int j = 0; j < 16; j += 4) {
        *(float4*)&bias[j] = *(const float4*)&b[c0 + j];
        *(float4*)&sc[j]   = *(const float4*)&scale[c0 + j];
        *(float4*)&of[j]   = *(const float4*)&offset[c0 + j];
        *(float4*)&attw[j] = *(const float4*)&att[h * 64 + o * 32 + kbase + j];
    }

#pragma unroll
    for (int mm = 0; mm < 2; ++mm) {
        float* accp = mm ? acc1 : acc0;
        float x[16];
        float s1 = 0.f, s2 = 0.f, sa = 0.f;
#pragma unroll
        for (int j = 0; j < 16; ++j) {
            float v = fmaxf(accp[j] + bias[j], 0.f);
            x[j] = v;
            s1 += v; s2 += v * v; sa += v * attw[j];
        }
        s1 += __shfl_xor(s1, 1);
        s2 += __shfl_xor(s2, 1);
        sa += __shfl_xor(sa, 1);
        float mean = s1 * (1.f / 32.f);
        float var  = s2 * (1.f / 32.f) - mean * mean;
        float rstd = rsqrtf(fmaxf(var, 0.f) + LN_EPS);
        float a_out = sa >= 0.f ? sa : 0.2f * sa;
        int n = base + m0 + mm;

        if (o == 0) {
#pragma unroll
            for (int j = 0; j < 16; ++j)
                x[j] = (x[j] - mean) * rstd * sc[j] + of[j];
#pragma unroll
            for (int j = 0; j < 16; j += 4)
                *(float4*)&out[n * COUT + c0 + j] = *(float4*)&x[j];
            if (kbase == 0) att_s[h * N_NODES + n] = a_out;
        } else {
#pragma unroll
            for (int j = 0; j < 16; j += 4)
                *(float4*)&feat_nei[n * 128 + (c0 - 128) + j] = *(float4*)&x[j];
            if (kbase == 0) att_n[h * N_NODES + n] = a_out;
        }
    }
}

// ---------------------------------------------------------------------------
// CSR build step 1: histogram of rows.
// ---------------------------------------------------------------------------
__global__ __launch_bounds__(256) void hist_kernel(const int* __restrict__ row,
                                                   int* __restrict__ cnt) {
    int e = blockIdx.x * 256 + threadIdx.x;   // grid sized exactly E
    atomicAdd(&cnt[row[e]], 1);
}

// ---------------------------------------------------------------------------
// CSR build step 2: exclusive scan of cnt -> start, pos (one 1024-thr block).
// ---------------------------------------------------------------------------
__global__ __launch_bounds__(1024) void scan_kernel(const int* __restrict__ cnt,
                                                    int* __restrict__ start,
                                                    int* __restrict__ pos) {
    const int CH = (N_NODES + 1023) / 1024;   // 98
    int t = threadIdx.x;
    int lo = t * CH, hi = min(lo + CH, N_NODES);
    int sum = 0;
    for (int i = lo; i < hi; ++i) sum += cnt[i];
    __shared__ int s[1024];
    s[t] = sum;
    __syncthreads();
#pragma unroll
    for (int off = 1; off < 1024; off <<= 1) {
        int v = (t >= off) ? s[t - off] : 0;
        __syncthreads();
        s[t] += v;
        __syncthreads();
    }
    int run = s[t] - sum;                      // exclusive prefix of this chunk
    for (int i = lo; i < hi; ++i) {
        start[i] = run;
        pos[i]   = run;
        run += cnt[i];
    }
}

// ---------------------------------------------------------------------------
// CSR build step 3: scatter edges into row segments as int2{col, adj_bits}.
// ---------------------------------------------------------------------------
__global__ __launch_bounds__(256) void scatter_kernel(
    const int* __restrict__ row, const int* __restrict__ col,
    const float* __restrict__ adj, int* __restrict__ pos,
    int2* __restrict__ eca) {
    int e = blockIdx.x * 256 + threadIdx.x;   // grid sized exactly E
    int r = row[e];
    int slot = atomicAdd(&pos[r], 1);
    eca[slot] = make_int2(col[e], __float_as_int(adj[e]));
}

// ---------------------------------------------------------------------------
// Gather: one wave per node. lane l -> channels 2l,2l+1 (h = l>>4).
// agg = sum_e (att_s[h][n] + att_n[h][col]) * adj * feat_nei[col]
// then fused LayerNorm per (n,h) group of 32 channels -> out[:,128:256].
// ---------------------------------------------------------------------------
__global__ __launch_bounds__(256) void gather_kernel(
    const int* __restrict__ start, const int* __restrict__ cnt,
    const int2* __restrict__ eca,
    const float* __restrict__ att_s, const float* __restrict__ att_n,
    const float* __restrict__ feat_nei,
    const float* __restrict__ scale, const float* __restrict__ offset,
    float* __restrict__ out)
{
    int w = threadIdx.x >> 6;
    int l = threadIdx.x & 63;
    int n = blockIdx.x * 4 + w;
    if (n >= N_NODES) return;
    int h  = l >> 4;
    int c2 = l * 2;
    float a_s = att_s[h * N_NODES + n];
    int s0 = start[n], d = cnt[n];
    float ax = 0.f, ay = 0.f;
    for (int i = 0; i < d; ++i) {
        int2 p = eca[s0 + i];
        int c = p.x;
        float av = __int_as_float(p.y);
        float wgt = (a_s + att_n[h * N_NODES + c]) * av;
        float2 f = *(const float2*)&feat_nei[c * 128 + c2];
        ax = fmaf(wgt, f.x, ax);
        ay = fmaf(wgt, f.y, ay);
    }
    float s1 = ax + ay, s2 = ax * ax + ay * ay;
#pragma unroll
    for (int off = 1; off < 16; off <<= 1) {
        s1 += __shfl_xor(s1, off);
        s2 += __shfl_xor(s2, off);
    }
    float mean = s1 * (1.f / 32.f);
    float var  = s2 * (1.f / 32.f) - mean * mean;
    float rstd = rsqrtf(fmaxf(var, 0.f) + LN_EPS);
    int ci = 128 + c2;
    float2 o2;
    o2.x = (ax - mean) * rstd * scale[ci]     + offset[ci];
    o2.y = (ay - mean) * rstd * scale[ci + 1] + offset[ci + 1];
    *(float2*)&out[n * COUT + ci] = o2;
}

// ---------------------------------------------------------------------------
extern "C" void kernel_launch(void* const* d_in, const int* in_sizes, int n_in,
                              void* d_out, int out_size, void* d_ws, size_t ws_size,
                              hipStream_t stream)
{
    const float* feat_in = (const float*)d_in[0];
    const int*   row     = (const int*)d_in[1];
    const int*   col     = (const int*)d_in[2];
    const float* adj     = (const float*)d_in[3];
    const float* W       = (const float*)d_in[4];
    const float* b       = (const float*)d_in[5];
    const float* att     = (const float*)d_in[6];
    const float* scale   = (const float*)d_in[7];
    const float* offset  = (const float*)d_in[8];
    float* out = (float*)d_out;

    float* ws       = (float*)d_ws;
    float* Wt       = ws;                            // 65536
    float* att_s    = Wt + 65536;                    // 400000
    float* att_n    = att_s + NH * N_NODES;          // 400000
    float* feat_nei = att_n + NH * N_NODES;          // 12,800,000
    int*   cnt      = (int*)(feat_nei + (size_t)N_NODES * 128);  // 100000
    int*   startp   = cnt + N_NODES;                 // 100000
    int*   pos      = startp + N_NODES;              // 100000
    int2*  eca      = (int2*)(pos + N_NODES);        // E int2 (8B-aligned)
    // total ws ~ 68.7 MB

    hipMemsetAsync(cnt, 0, N_NODES * sizeof(int), stream);
    wt_kernel<<<256, 256, 0, stream>>>(W, Wt);
    gemm_kernel<<<N_NODES / 32, 256, 0, stream>>>(feat_in, Wt, b, att, scale,
                                                  offset, out, feat_nei, att_s, att_n);
    hist_kernel<<<E_EDGES / 256, 256, 0, stream>>>(row, cnt);
    scan_kernel<<<1, 1024, 0, stream>>>(cnt, startp, pos);
    scatter_kernel<<<E_EDGES / 256, 256, 0, stream>>>(row, col, adj, pos, eca);
    gather_kernel<<<(N_NODES + 3) / 4, 256, 0, stream>>>(startp, cnt, eca, att_s,
                                                         att_n, feat_nei, scale,
                                                         offset, out);
}

// Round 6
// 851.004 us; speedup vs baseline: 3.8854x; 1.3566x over previous
//
#include <hip/hip_runtime.h>

#define N_NODES 100000
#define E_EDGES 1600000
#define DIN 256
#define NH 4
#define DH 32
#define COUT 256
#define LN_EPS 1e-9f
#define BM 64
#define BK 32
#define KPAD (BK + 8)

typedef __attribute__((ext_vector_type(4))) float  f32x4;
typedef __attribute__((ext_vector_type(8))) short  bf16x8;
typedef __attribute__((ext_vector_type(8))) ushort u16x8;

__device__ __forceinline__ ushort f2bf(float x) {
    union { float f; uint u; } v; v.f = x;
    uint r = v.u + 0x7fffu + ((v.u >> 16) & 1u);
    return (ushort)(r >> 16);
}
__device__ __forceinline__ float bf2f(ushort h) {
    union { uint u; float f; } v; v.u = ((uint)h) << 16;
    return v.f;
}

// ---------------------------------------------------------------------------
// W (2,4,256,32) f32 -> Wn_hi/Wn_lo [c][k] bf16 (N x K), c = o*128+h*32+q
// hi = bf16(w), lo = bf16(w - hi)
// ---------------------------------------------------------------------------
__global__ __launch_bounds__(256) void wn_kernel(const float* __restrict__ W,
                                                 ushort* __restrict__ Wn_hi,
                                                 ushort* __restrict__ Wn_lo) {
    int i = blockIdx.x * 256 + threadIdx.x;   // 65536
    int c = i >> 8, k = i & 255;
    int o = c >> 7, h = (c >> 5) & 3, q = c & 31;
    float w = W[((o * NH + h) * DIN + k) * DH + q];
    ushort hi = f2bf(w);
    Wn_hi[i] = hi;
    Wn_lo[i] = f2bf(w - bf2f(hi));
}

// ---------------------------------------------------------------------------
// Split-bf16 MFMA GEMM: block = 64 rows x 256 cols, K=256 in 8 steps of 32.
// acc += a_hi*b_hi + a_lo*b_hi + a_hi*b_lo  (~f32 precision).
// 4 waves; wave wid owns cols [wid*64, wid*64+64). acc 4x4 frags 16x16x32.
// Fused epilogue: ReLU + per-head LN / att logits.
// ---------------------------------------------------------------------------
__global__ __launch_bounds__(256) void gemm_kernel(
    const float* __restrict__ feat_in,
    const ushort* __restrict__ Wn_hi, const ushort* __restrict__ Wn_lo,
    const float* __restrict__ b, const float* __restrict__ att,
    const float* __restrict__ scale, const float* __restrict__ offset,
    float* __restrict__ out, float* __restrict__ feat_nei,
    float* __restrict__ att_s, float* __restrict__ att_n)
{
    __shared__ ushort sAh[BM][KPAD];    // 5 KB
    __shared__ ushort sAl[BM][KPAD];    // 5 KB
    __shared__ ushort sBh[256][KPAD];   // 20 KB
    __shared__ ushort sBl[256][KPAD];   // 20 KB

    const int t   = threadIdx.x;
    const int wid = t >> 6;
    const int l   = t & 63;
    const int l15 = l & 15;
    const int lhi = l >> 4;
    const int m_blk = blockIdx.x * BM;

    f32x4 acc[4][4] = {};   // [mi][ni]

    // A staging: thread -> (row = t>>2, k-octet = t&3), 8 f32 -> hi/lo bf16
    const int arow = t >> 2;
    const int akq  = t & 3;
    const int arow_g = min(m_blk + arow, N_NODES - 1);
    const float* aptr = feat_in + (size_t)arow_g * DIN + akq * 8;

    for (int kc = 0; kc < DIN; kc += BK) {
        float4 f0 = *(const float4*)(aptr + kc);
        float4 f1 = *(const float4*)(aptr + kc + 4);
        float fv[8] = { f0.x, f0.y, f0.z, f0.w, f1.x, f1.y, f1.z, f1.w };
        u16x8 ph, pl;
#pragma unroll
        for (int j = 0; j < 8; ++j) {
            ushort hi = f2bf(fv[j]);
            ph[j] = hi;
            pl[j] = f2bf(fv[j] - bf2f(hi));
        }
        *(u16x8*)&sAh[arow][akq * 8] = ph;
        *(u16x8*)&sAl[arow][akq * 8] = pl;

        // B staging: per plane 256 rows x 32 k = 1024 u16x8 chunks
#pragma unroll
        for (int i = 0; i < 4; ++i) {
            int c = i * 256 + t;
            int rrow = c >> 2, koff = (c & 3) * 8;
            *(u16x8*)&sBh[rrow][koff] =
                *(const u16x8*)(Wn_hi + rrow * 256 + kc + koff);
            *(u16x8*)&sBl[rrow][koff] =
                *(const u16x8*)(Wn_lo + rrow * 256 + kc + koff);
        }
        __syncthreads();

        bf16x8 ah[4], al[4], bh[4], bl[4];
#pragma unroll
        for (int mi = 0; mi < 4; ++mi) {
            ah[mi] = *(bf16x8*)&sAh[mi * 16 + l15][lhi * 8];
            al[mi] = *(bf16x8*)&sAl[mi * 16 + l15][lhi * 8];
        }
#pragma unroll
        for (int ni = 0; ni < 4; ++ni) {
            bh[ni] = *(bf16x8*)&sBh[wid * 64 + ni * 16 + l15][lhi * 8];
            bl[ni] = *(bf16x8*)&sBl[wid * 64 + ni * 16 + l15][lhi * 8];
        }
#pragma unroll
        for (int mi = 0; mi < 4; ++mi)
#pragma unroll
            for (int ni = 0; ni < 4; ++ni) {
                acc[mi][ni] = __builtin_amdgcn_mfma_f32_16x16x32_bf16(
                    al[mi], bh[ni], acc[mi][ni], 0, 0, 0);
                acc[mi][ni] = __builtin_amdgcn_mfma_f32_16x16x32_bf16(
                    ah[mi], bl[ni], acc[mi][ni], 0, 0, 0);
                acc[mi][ni] = __builtin_amdgcn_mfma_f32_16x16x32_bf16(
                    ah[mi], bh[ni], acc[mi][ni], 0, 0, 0);
            }
        __syncthreads();
    }

    // ---- epilogue ----
    const int o = wid >> 1;
    float bias[4], attw[4], sc[4], of[4];
#pragma unroll
    for (int ni = 0; ni < 4; ++ni) {
        int c = wid * 64 + ni * 16 + l15;
        int h = (c >> 5) & 3;
        bias[ni] = b[c];
        sc[ni]   = scale[c];
        of[ni]   = offset[c];
        attw[ni] = att[h * 64 + o * 32 + (c & 31)];
    }

#pragma unroll
    for (int mi = 0; mi < 4; ++mi) {
#pragma unroll
        for (int r = 0; r < 4; ++r) {
            int row = m_blk + mi * 16 + lhi * 4 + r;
            float v[4];
#pragma unroll
            for (int ni = 0; ni < 4; ++ni)
                v[ni] = fmaxf(acc[mi][ni][r] + bias[ni], 0.f);
#pragma unroll
            for (int p = 0; p < 2; ++p) {
                float x0 = v[2 * p], x1 = v[2 * p + 1];
                float s1 = x0 + x1;
                float s2 = x0 * x0 + x1 * x1;
                float sa = x0 * attw[2 * p] + x1 * attw[2 * p + 1];
#pragma unroll
                for (int off = 1; off < 16; off <<= 1) {
                    s1 += __shfl_xor(s1, off);
                    s2 += __shfl_xor(s2, off);
                    sa += __shfl_xor(sa, off);
                }
                float mean = s1 * (1.f / 32.f);
                float var  = s2 * (1.f / 32.f) - mean * mean;
                float rstd = rsqrtf(fmaxf(var, 0.f) + LN_EPS);
                float a_out = sa >= 0.f ? sa : 0.2f * sa;
                if (row < N_NODES) {
                    int hloc = (wid & 1) * 2 + p;
                    if (o == 0) {
#pragma unroll
                        for (int q = 0; q < 2; ++q) {
                            int ni = 2 * p + q;
                            int c = wid * 64 + ni * 16 + l15;
                            out[(size_t)row * COUT + c] =
                                (v[ni] - mean) * rstd * sc[ni] + of[ni];
                        }
                        if (l15 == 0) att_s[hloc * N_NODES + row] = a_out;
                    } else {
#pragma unroll
                        for (int q = 0; q < 2; ++q) {
                            int ni = 2 * p + q;
                            int c = wid * 64 + ni * 16 + l15 - 128;
                            feat_nei[(size_t)row * 128 + c] = v[ni];
                        }
                        if (l15 == 0) att_n[hloc * N_NODES + row] = a_out;
                    }
                }
            }
        }
    }
}

// ---------------------------------------------------------------------------
// CSR build step 1: histogram of rows.
// ---------------------------------------------------------------------------
__global__ __launch_bounds__(256) void hist_kernel(const int* __restrict__ row,
                                                   int* __restrict__ cnt) {
    int e = blockIdx.x * 256 + threadIdx.x;
    atomicAdd(&cnt[row[e]], 1);
}

// ---------------------------------------------------------------------------
// CSR build step 2: exclusive scan of cnt -> start, pos (one 1024-thr block).
// ---------------------------------------------------------------------------
__global__ __launch_bounds__(1024) void scan_kernel(const int* __restrict__ cnt,
                                                    int* __restrict__ start,
                                                    int* __restrict__ pos) {
    const int CH = (N_NODES + 1023) / 1024;
    int t = threadIdx.x;
    int lo = t * CH, hi = min(lo + CH, N_NODES);
    int sum = 0;
    for (int i = lo; i < hi; ++i) sum += cnt[i];
    __shared__ int s[1024];
    s[t] = sum;
    __syncthreads();
#pragma unroll
    for (int off = 1; off < 1024; off <<= 1) {
        int v = (t >= off) ? s[t - off] : 0;
        __syncthreads();
        s[t] += v;
        __syncthreads();
    }
    int run = s[t] - sum;
    for (int i = lo; i < hi; ++i) {
        start[i] = run;
        pos[i]   = run;
        run += cnt[i];
    }
}

// ---------------------------------------------------------------------------
// CSR build step 3: scatter edges into row segments as int2{col, adj_bits}.
// ---------------------------------------------------------------------------
__global__ __launch_bounds__(256) void scatter_kernel(
    const int* __restrict__ row, const int* __restrict__ col,
    const float* __restrict__ adj, int* __restrict__ pos,
    int2* __restrict__ eca) {
    int e = blockIdx.x * 256 + threadIdx.x;
    int r = row[e];
    int slot = atomicAdd(&pos[r], 1);
    eca[slot] = make_int2(col[e], __float_as_int(adj[e]));
}

// ---------------------------------------------------------------------------
// Gather: one wave per node; lane l -> channels 2l,2l+1 (h = l>>4);
// fused LayerNorm -> out[:,128:256].
// ---------------------------------------------------------------------------
__global__ __launch_bounds__(256) void gather_kernel(
    const int* __restrict__ start, const int* __restrict__ cnt,
    const int2* __restrict__ eca,
    const float* __restrict__ att_s, const float* __restrict__ att_n,
    const float* __restrict__ feat_nei,
    const float* __restrict__ scale, const float* __restrict__ offset,
    float* __restrict__ out)
{
    int w = threadIdx.x >> 6;
    int l = threadIdx.x & 63;
    int n = blockIdx.x * 4 + w;
    if (n >= N_NODES) return;
    int h  = l >> 4;
    int c2 = l * 2;
    float a_s = att_s[h * N_NODES + n];
    int s0 = start[n], d = cnt[n];
    float ax = 0.f, ay = 0.f;
    for (int i = 0; i < d; ++i) {
        int2 p = eca[s0 + i];
        int c = p.x;
        float av = __int_as_float(p.y);
        float wgt = (a_s + att_n[h * N_NODES + c]) * av;
        float2 f = *(const float2*)&feat_nei[c * 128 + c2];
        ax = fmaf(wgt, f.x, ax);
        ay = fmaf(wgt, f.y, ay);
    }
    float s1 = ax + ay, s2 = ax * ax + ay * ay;
#pragma unroll
    for (int off = 1; off < 16; off <<= 1) {
        s1 += __shfl_xor(s1, off);
        s2 += __shfl_xor(s2, off);
    }
    float mean = s1 * (1.f / 32.f);
    float var  = s2 * (1.f / 32.f) - mean * mean;
    float rstd = rsqrtf(fmaxf(var, 0.f) + LN_EPS);
    int ci = 128 + c2;
    float2 o2;
    o2.x = (ax - mean) * rstd * scale[ci]     + offset[ci];
    o2.y = (ay - mean) * rstd * scale[ci + 1] + offset[ci + 1];
    *(float2*)&out[n * COUT + ci] = o2;
}

// ---------------------------------------------------------------------------
extern "C" void kernel_launch(void* const* d_in, const int* in_sizes, int n_in,
                              void* d_out, int out_size, void* d_ws, size_t ws_size,
                              hipStream_t stream)
{
    const float* feat_in = (const float*)d_in[0];
    const int*   row     = (const int*)d_in[1];
    const int*   col     = (const int*)d_in[2];
    const float* adj     = (const float*)d_in[3];
    const float* W       = (const float*)d_in[4];
    const float* b       = (const float*)d_in[5];
    const float* att     = (const float*)d_in[6];
    const float* scale   = (const float*)d_in[7];
    const float* offset  = (const float*)d_in[8];
    float* out = (float*)d_out;

    float*  ws       = (float*)d_ws;
    ushort* Wn_hi    = (ushort*)ws;                  // 65536 ushort
    ushort* Wn_lo    = Wn_hi + 65536;                // 65536 ushort (= 65536 f32 total)
    float*  att_s    = ws + 65536;
    float*  att_n    = att_s + NH * N_NODES;
    float*  feat_nei = att_n + NH * N_NODES;
    int*    cnt      = (int*)(feat_nei + (size_t)N_NODES * 128);
    int*    startp   = cnt + N_NODES;
    int*    pos      = startp + N_NODES;
    int2*   eca      = (int2*)(pos + N_NODES);       // 8B aligned

    hipMemsetAsync(cnt, 0, N_NODES * sizeof(int), stream);
    wn_kernel<<<256, 256, 0, stream>>>(W, Wn_hi, Wn_lo);
    gemm_kernel<<<(N_NODES + BM - 1) / BM, 256, 0, stream>>>(
        feat_in, Wn_hi, Wn_lo, b, att, scale, offset, out, feat_nei, att_s, att_n);
    hist_kernel<<<E_EDGES / 256, 256, 0, stream>>>(row, cnt);
    scan_kernel<<<1, 1024, 0, stream>>>(cnt, startp, pos);
    scatter_kernel<<<E_EDGES / 256, 256, 0, stream>>>(row, col, adj, pos, eca);
    gather_kernel<<<(N_NODES + 3) / 4, 256, 0, stream>>>(startp, cnt, eca, att_s,
                                                         att_n, feat_nei, scale,
                                                         offset, out);
}

// Round 8
// 637.736 us; speedup vs baseline: 5.1848x; 1.3344x over previous
//
#include <hip/hip_runtime.h>

#define N_NODES 100000
#define E_EDGES 1600000
#define DIN 256
#define NH 4
#define DH 32
#define COUT 256
#define LN_EPS 1e-9f
#define BM 64
#define BK 32
#define KPAD (BK + 8)
#define NB 391   // ceil(N_NODES / 256)

typedef __attribute__((ext_vector_type(4))) float  f32x4;
typedef __attribute__((ext_vector_type(8))) short  bf16x8;
typedef __attribute__((ext_vector_type(8))) ushort u16x8;

__device__ __forceinline__ ushort f2bf(float x) {
    union { float f; uint u; } v; v.f = x;
    uint r = v.u + 0x7fffu + ((v.u >> 16) & 1u);
    return (ushort)(r >> 16);
}
__device__ __forceinline__ float bf2f(ushort h) {
    union { uint u; float f; } v; v.u = ((uint)h) << 16;
    return v.f;
}

// ---------------------------------------------------------------------------
// W (2,4,256,32) f32 -> Wn_hi/Wn_lo [c][k] bf16 (N x K), c = o*128+h*32+q
// ---------------------------------------------------------------------------
__global__ __launch_bounds__(256) void wn_kernel(const float* __restrict__ W,
                                                 ushort* __restrict__ Wn_hi,
                                                 ushort* __restrict__ Wn_lo) {
    int i = blockIdx.x * 256 + threadIdx.x;   // 65536
    int c = i >> 8, k = i & 255;
    int o = c >> 7, h = (c >> 5) & 3, q = c & 31;
    float w = W[((o * NH + h) * DIN + k) * DH + q];
    ushort hi = f2bf(w);
    Wn_hi[i] = hi;
    Wn_lo[i] = f2bf(w - bf2f(hi));
}

// ---------------------------------------------------------------------------
// Split-bf16 MFMA GEMM: block = 64 rows x 256 cols, K=256 in 8 steps of 32.
// acc += a_hi*b_hi + a_lo*b_hi + a_hi*b_lo  (~f32 precision).
// ---------------------------------------------------------------------------
__global__ __launch_bounds__(256) void gemm_kernel(
    const float* __restrict__ feat_in,
    const ushort* __restrict__ Wn_hi, const ushort* __restrict__ Wn_lo,
    const float* __restrict__ b, const float* __restrict__ att,
    const float* __restrict__ scale, const float* __restrict__ offset,
    float* __restrict__ out, float* __restrict__ feat_nei,
    float* __restrict__ att_s, float* __restrict__ att_n)
{
    __shared__ ushort sAh[BM][KPAD];
    __shared__ ushort sAl[BM][KPAD];
    __shared__ ushort sBh[256][KPAD];
    __shared__ ushort sBl[256][KPAD];

    const int t   = threadIdx.x;
    const int wid = t >> 6;
    const int l   = t & 63;
    const int l15 = l & 15;
    const int lhi = l >> 4;
    const int m_blk = blockIdx.x * BM;

    f32x4 acc[4][4] = {};

    const int arow = t >> 2;
    const int akq  = t & 3;
    const int arow_g = min(m_blk + arow, N_NODES - 1);
    const float* aptr = feat_in + (size_t)arow_g * DIN + akq * 8;

    for (int kc = 0; kc < DIN; kc += BK) {
        float4 f0 = *(const float4*)(aptr + kc);
        float4 f1 = *(const float4*)(aptr + kc + 4);
        float fv[8] = { f0.x, f0.y, f0.z, f0.w, f1.x, f1.y, f1.z, f1.w };
        u16x8 ph, pl;
#pragma unroll
        for (int j = 0; j < 8; ++j) {
            ushort hi = f2bf(fv[j]);
            ph[j] = hi;
            pl[j] = f2bf(fv[j] - bf2f(hi));
        }
        *(u16x8*)&sAh[arow][akq * 8] = ph;
        *(u16x8*)&sAl[arow][akq * 8] = pl;

#pragma unroll
        for (int i = 0; i < 4; ++i) {
            int c = i * 256 + t;
            int rrow = c >> 2, koff = (c & 3) * 8;
            *(u16x8*)&sBh[rrow][koff] =
                *(const u16x8*)(Wn_hi + rrow * 256 + kc + koff);
            *(u16x8*)&sBl[rrow][koff] =
                *(const u16x8*)(Wn_lo + rrow * 256 + kc + koff);
        }
        __syncthreads();

        bf16x8 ah[4], al[4], bh[4], bl[4];
#pragma unroll
        for (int mi = 0; mi < 4; ++mi) {
            ah[mi] = *(bf16x8*)&sAh[mi * 16 + l15][lhi * 8];
            al[mi] = *(bf16x8*)&sAl[mi * 16 + l15][lhi * 8];
        }
#pragma unroll
        for (int ni = 0; ni < 4; ++ni) {
            bh[ni] = *(bf16x8*)&sBh[wid * 64 + ni * 16 + l15][lhi * 8];
            bl[ni] = *(bf16x8*)&sBl[wid * 64 + ni * 16 + l15][lhi * 8];
        }
#pragma unroll
        for (int mi = 0; mi < 4; ++mi)
#pragma unroll
            for (int ni = 0; ni < 4; ++ni) {
                acc[mi][ni] = __builtin_amdgcn_mfma_f32_16x16x32_bf16(
                    al[mi], bh[ni], acc[mi][ni], 0, 0, 0);
                acc[mi][ni] = __builtin_amdgcn_mfma_f32_16x16x32_bf16(
                    ah[mi], bl[ni], acc[mi][ni], 0, 0, 0);
                acc[mi][ni] = __builtin_amdgcn_mfma_f32_16x16x32_bf16(
                    ah[mi], bh[ni], acc[mi][ni], 0, 0, 0);
            }
        __syncthreads();
    }

    // ---- epilogue ----
    const int o = wid >> 1;
    float bias[4], attw[4], sc[4], of[4];
#pragma unroll
    for (int ni = 0; ni < 4; ++ni) {
        int c = wid * 64 + ni * 16 + l15;
        int h = (c >> 5) & 3;
        bias[ni] = b[c];
        sc[ni]   = scale[c];
        of[ni]   = offset[c];
        attw[ni] = att[h * 64 + o * 32 + (c & 31)];
    }

#pragma unroll
    for (int mi = 0; mi < 4; ++mi) {
#pragma unroll
        for (int r = 0; r < 4; ++r) {
            int row = m_blk + mi * 16 + lhi * 4 + r;
            float v[4];
#pragma unroll
            for (int ni = 0; ni < 4; ++ni)
                v[ni] = fmaxf(acc[mi][ni][r] + bias[ni], 0.f);
#pragma unroll
            for (int p = 0; p < 2; ++p) {
                float x0 = v[2 * p], x1 = v[2 * p + 1];
                float s1 = x0 + x1;
                float s2 = x0 * x0 + x1 * x1;
                float sa = x0 * attw[2 * p] + x1 * attw[2 * p + 1];
#pragma unroll
                for (int off = 1; off < 16; off <<= 1) {
                    s1 += __shfl_xor(s1, off);
                    s2 += __shfl_xor(s2, off);
                    sa += __shfl_xor(sa, off);
                }
                float mean = s1 * (1.f / 32.f);
                float var  = s2 * (1.f / 32.f) - mean * mean;
                float rstd = rsqrtf(fmaxf(var, 0.f) + LN_EPS);
                float a_out = sa >= 0.f ? sa : 0.2f * sa;
                if (row < N_NODES) {
                    int hloc = (wid & 1) * 2 + p;
                    if (o == 0) {
#pragma unroll
                        for (int q = 0; q < 2; ++q) {
                            int ni = 2 * p + q;
                            int c = wid * 64 + ni * 16 + l15;
                            out[(size_t)row * COUT + c] =
                                (v[ni] - mean) * rstd * sc[ni] + of[ni];
                        }
                        if (l15 == 0) att_s[hloc * N_NODES + row] = a_out;
                    } else {
#pragma unroll
                        for (int q = 0; q < 2; ++q) {
                            int ni = 2 * p + q;
                            int c = wid * 64 + ni * 16 + l15 - 128;
                            feat_nei[(size_t)row * 128 + c] = v[ni];
                        }
                        if (l15 == 0) att_n[hloc * N_NODES + row] = a_out;
                    }
                }
            }
        }
    }
}

// ---------------------------------------------------------------------------
// CSR build step 1: histogram of rows.
// ---------------------------------------------------------------------------
__global__ __launch_bounds__(256) void hist_kernel(const int* __restrict__ row,
                                                   int* __restrict__ cnt) {
    int e = blockIdx.x * 256 + threadIdx.x;
    atomicAdd(&cnt[row[e]], 1);
}

// ---------------------------------------------------------------------------
// Hierarchical scan (3 kernels): per-block sums -> scan sums -> final.
// ---------------------------------------------------------------------------
__global__ __launch_bounds__(256) void scan1_kernel(const int* __restrict__ cnt,
                                                    int* __restrict__ bsum) {
    int i = blockIdx.x * 256 + threadIdx.x;
    int v = (i < N_NODES) ? cnt[i] : 0;
#pragma unroll
    for (int off = 1; off < 64; off <<= 1) v += __shfl_xor(v, off);
    __shared__ int s[4];
    if ((threadIdx.x & 63) == 0) s[threadIdx.x >> 6] = v;
    __syncthreads();
    if (threadIdx.x == 0) bsum[blockIdx.x] = s[0] + s[1] + s[2] + s[3];
}

__global__ __launch_bounds__(512) void scan2_kernel(const int* __restrict__ bsum,
                                                    int* __restrict__ boff) {
    __shared__ int s[512];
    int t = threadIdx.x;
    int v = (t < NB) ? bsum[t] : 0;
    s[t] = v;
    __syncthreads();
#pragma unroll
    for (int off = 1; off < 512; off <<= 1) {
        int u = (t >= off) ? s[t - off] : 0;
        __syncthreads();
        s[t] += u;
        __syncthreads();
    }
    if (t < NB) boff[t] = s[t] - v;   // exclusive prefix
}

__global__ __launch_bounds__(256) void scan3_kernel(const int* __restrict__ cnt,
                                                    const int* __restrict__ boff,
                                                    int* __restrict__ start,
                                                    int* __restrict__ pos) {
    __shared__ int s[256];
    int t = threadIdx.x;
    int i = blockIdx.x * 256 + t;
    int v = (i < N_NODES) ? cnt[i] : 0;
    s[t] = v;
    __syncthreads();
#pragma unroll
    for (int off = 1; off < 256; off <<= 1) {
        int u = (t >= off) ? s[t - off] : 0;
        __syncthreads();
        s[t] += u;
        __syncthreads();
    }
    if (i < N_NODES) {
        int e = boff[blockIdx.x] + s[t] - v;   // global exclusive prefix
        start[i] = e;
        pos[i]   = e;
    }
}

// ---------------------------------------------------------------------------
// CSR build step 3: scatter edges into row segments as int2{col, adj_bits}.
// ---------------------------------------------------------------------------
__global__ __launch_bounds__(256) void scatter_kernel(
    const int* __restrict__ row, const int* __restrict__ col,
    const float* __restrict__ adj, int* __restrict__ pos,
    int2* __restrict__ eca) {
    int e = blockIdx.x * 256 + threadIdx.x;
    int r = row[e];
    int slot = atomicAdd(&pos[r], 1);
    eca[slot] = make_int2(col[e], __float_as_int(adj[e]));
}

// ---------------------------------------------------------------------------
// Gather: one wave per node; lane l -> channels 2l,2l+1 (h = l>>4);
// fused LayerNorm -> out[:,128:256].
// ---------------------------------------------------------------------------
__global__ __launch_bounds__(256) void gather_kernel(
    const int* __restrict__ start, const int* __restrict__ cnt,
    const int2* __restrict__ eca,
    const float* __restrict__ att_s, const float* __restrict__ att_n,
    const float* __restrict__ feat_nei,
    const float* __restrict__ scale, const float* __restrict__ offset,
    float* __restrict__ out)
{
    int w = threadIdx.x >> 6;
    int l = threadIdx.x & 63;
    int n = blockIdx.x * 4 + w;
    if (n >= N_NODES) return;
    int h  = l >> 4;
    int c2 = l * 2;
    float a_s = att_s[h * N_NODES + n];
    int s0 = start[n], d = cnt[n];
    float ax = 0.f, ay = 0.f;
    for (int i = 0; i < d; ++i) {
        int2 p = eca[s0 + i];
        int c = p.x;
        float av = __int_as_float(p.y);
        float wgt = (a_s + att_n[h * N_NODES + c]) * av;
        float2 f = *(const float2*)&feat_nei[c * 128 + c2];
        ax = fmaf(wgt, f.x, ax);
        ay = fmaf(wgt, f.y, ay);
    }
    float s1 = ax + ay, s2 = ax * ax + ay * ay;
#pragma unroll
    for (int off = 1; off < 16; off <<= 1) {
        s1 += __shfl_xor(s1, off);
        s2 += __shfl_xor(s2, off);
    }
    float mean = s1 * (1.f / 32.f);
    float var  = s2 * (1.f / 32.f) - mean * mean;
    float rstd = rsqrtf(fmaxf(var, 0.f) + LN_EPS);
    int ci = 128 + c2;
    float2 o2;
    o2.x = (ax - mean) * rstd * scale[ci]     + offset[ci];
    o2.y = (ay - mean) * rstd * scale[ci + 1] + offset[ci + 1];
    *(float2*)&out[n * COUT + ci] = o2;
}

// ---------------------------------------------------------------------------
extern "C" void kernel_launch(void* const* d_in, const int* in_sizes, int n_in,
                              void* d_out, int out_size, void* d_ws, size_t ws_size,
                              hipStream_t stream)
{
    const float* feat_in = (const float*)d_in[0];
    const int*   row     = (const int*)d_in[1];
    const int*   col     = (const int*)d_in[2];
    const float* adj     = (const float*)d_in[3];
    const float* W       = (const float*)d_in[4];
    const float* b       = (const float*)d_in[5];
    const float* att     = (const float*)d_in[6];
    const float* scale   = (const float*)d_in[7];
    const float* offset  = (const float*)d_in[8];
    float* out = (float*)d_out;

    float*  ws       = (float*)d_ws;
    ushort* Wn_hi    = (ushort*)ws;                  // 65536 ushort
    ushort* Wn_lo    = Wn_hi + 65536;                // 65536 ushort
    float*  att_s    = ws + 65536;
    float*  att_n    = att_s + NH * N_NODES;
    float*  feat_nei = att_n + NH * N_NODES;
    int*    cnt      = (int*)(feat_nei + (size_t)N_NODES * 128);
    int*    startp   = cnt + N_NODES;
    int*    pos      = startp + N_NODES;
    int*    bsum     = pos + N_NODES;                // 392 (padded even)
    int*    boff     = bsum + 392;                   // 392
    int2*   eca      = (int2*)(boff + 392);          // 8B aligned (300784 ints before)

    hipMemsetAsync(cnt, 0, N_NODES * sizeof(int), stream);
    wn_kernel<<<256, 256, 0, stream>>>(W, Wn_hi, Wn_lo);
    gemm_kernel<<<(N_NODES + BM - 1) / BM, 256, 0, stream>>>(
        feat_in, Wn_hi, Wn_lo, b, att, scale, offset, out, feat_nei, att_s, att_n);
    hist_kernel<<<E_EDGES / 256, 256, 0, stream>>>(row, cnt);
    scan1_kernel<<<NB, 256, 0, stream>>>(cnt, bsum);
    scan2_kernel<<<1, 512, 0, stream>>>(bsum, boff);
    scan3_kernel<<<NB, 256, 0, stream>>>(cnt, boff, startp, pos);
    scatter_kernel<<<E_EDGES / 256, 256, 0, stream>>>(row, col, adj, pos, eca);
    gather_kernel<<<(N_NODES + 3) / 4, 256, 0, stream>>>(startp, cnt, eca, att_s,
                                                         att_n, feat_nei, scale,
                                                         offset, out);
}

// Round 9
// 568.782 us; speedup vs baseline: 5.8133x; 1.1212x over previous
//
#include <hip/hip_runtime.h>

#define N_NODES 100000
#define E_EDGES 1600000
#define DIN 256
#define NH 4
#define DH 32
#define COUT 256
#define LN_EPS 1e-9f
#define BM 64
#define BK 32
#define KPAD (BK + 8)
#define NB 391   // ceil(N_NODES / 256)

typedef __attribute__((ext_vector_type(4))) float  f32x4;
typedef __attribute__((ext_vector_type(8))) short  bf16x8;
typedef __attribute__((ext_vector_type(8))) ushort u16x8;

__device__ __forceinline__ ushort f2bf(float x) {
    union { float f; uint u; } v; v.f = x;
    uint r = v.u + 0x7fffu + ((v.u >> 16) & 1u);
    return (ushort)(r >> 16);
}
__device__ __forceinline__ float bf2f(ushort h) {
    union { uint u; float f; } v; v.u = ((uint)h) << 16;
    return v.f;
}

// ---------------------------------------------------------------------------
// W (2,4,256,32) f32 -> Wn_hi/Wn_lo [c][k] bf16 (N x K), c = o*128+h*32+q
// ---------------------------------------------------------------------------
__global__ __launch_bounds__(256) void wn_kernel(const float* __restrict__ W,
                                                 ushort* __restrict__ Wn_hi,
                                                 ushort* __restrict__ Wn_lo) {
    int i = blockIdx.x * 256 + threadIdx.x;   // 65536
    int c = i >> 8, k = i & 255;
    int o = c >> 7, h = (c >> 5) & 3, q = c & 31;
    float w = W[((o * NH + h) * DIN + k) * DH + q];
    ushort hi = f2bf(w);
    Wn_hi[i] = hi;
    Wn_lo[i] = f2bf(w - bf2f(hi));
}

// ---------------------------------------------------------------------------
// Split-bf16 MFMA GEMM: block = 64 rows x 256 cols, K=256 in 8 steps of 32.
// acc += a_hi*b_hi + a_lo*b_hi + a_hi*b_lo  (~f32 precision).
// feat_nei is now written as rounded bf16 (ushort).
// ---------------------------------------------------------------------------
__global__ __launch_bounds__(256) void gemm_kernel(
    const float* __restrict__ feat_in,
    const ushort* __restrict__ Wn_hi, const ushort* __restrict__ Wn_lo,
    const float* __restrict__ b, const float* __restrict__ att,
    const float* __restrict__ scale, const float* __restrict__ offset,
    float* __restrict__ out, ushort* __restrict__ feat_nei,
    float* __restrict__ att_s, float* __restrict__ att_n)
{
    __shared__ ushort sAh[BM][KPAD];
    __shared__ ushort sAl[BM][KPAD];
    __shared__ ushort sBh[256][KPAD];
    __shared__ ushort sBl[256][KPAD];

    const int t   = threadIdx.x;
    const int wid = t >> 6;
    const int l   = t & 63;
    const int l15 = l & 15;
    const int lhi = l >> 4;
    const int m_blk = blockIdx.x * BM;

    f32x4 acc[4][4] = {};

    const int arow = t >> 2;
    const int akq  = t & 3;
    const int arow_g = min(m_blk + arow, N_NODES - 1);
    const float* aptr = feat_in + (size_t)arow_g * DIN + akq * 8;

    for (int kc = 0; kc < DIN; kc += BK) {
        float4 f0 = *(const float4*)(aptr + kc);
        float4 f1 = *(const float4*)(aptr + kc + 4);
        float fv[8] = { f0.x, f0.y, f0.z, f0.w, f1.x, f1.y, f1.z, f1.w };
        u16x8 ph, pl;
#pragma unroll
        for (int j = 0; j < 8; ++j) {
            ushort hi = f2bf(fv[j]);
            ph[j] = hi;
            pl[j] = f2bf(fv[j] - bf2f(hi));
        }
        *(u16x8*)&sAh[arow][akq * 8] = ph;
        *(u16x8*)&sAl[arow][akq * 8] = pl;

#pragma unroll
        for (int i = 0; i < 4; ++i) {
            int c = i * 256 + t;
            int rrow = c >> 2, koff = (c & 3) * 8;
            *(u16x8*)&sBh[rrow][koff] =
                *(const u16x8*)(Wn_hi + rrow * 256 + kc + koff);
            *(u16x8*)&sBl[rrow][koff] =
                *(const u16x8*)(Wn_lo + rrow * 256 + kc + koff);
        }
        __syncthreads();

        bf16x8 ah[4], al[4], bh[4], bl[4];
#pragma unroll
        for (int mi = 0; mi < 4; ++mi) {
            ah[mi] = *(bf16x8*)&sAh[mi * 16 + l15][lhi * 8];
            al[mi] = *(bf16x8*)&sAl[mi * 16 + l15][lhi * 8];
        }
#pragma unroll
        for (int ni = 0; ni < 4; ++ni) {
            bh[ni] = *(bf16x8*)&sBh[wid * 64 + ni * 16 + l15][lhi * 8];
            bl[ni] = *(bf16x8*)&sBl[wid * 64 + ni * 16 + l15][lhi * 8];
        }
#pragma unroll
        for (int mi = 0; mi < 4; ++mi)
#pragma unroll
            for (int ni = 0; ni < 4; ++ni) {
                acc[mi][ni] = __builtin_amdgcn_mfma_f32_16x16x32_bf16(
                    al[mi], bh[ni], acc[mi][ni], 0, 0, 0);
                acc[mi][ni] = __builtin_amdgcn_mfma_f32_16x16x32_bf16(
                    ah[mi], bl[ni], acc[mi][ni], 0, 0, 0);
                acc[mi][ni] = __builtin_amdgcn_mfma_f32_16x16x32_bf16(
                    ah[mi], bh[ni], acc[mi][ni], 0, 0, 0);
            }
        __syncthreads();
    }

    // ---- epilogue ----
    const int o = wid >> 1;
    float bias[4], attw[4], sc[4], of[4];
#pragma unroll
    for (int ni = 0; ni < 4; ++ni) {
        int c = wid * 64 + ni * 16 + l15;
        int h = (c >> 5) & 3;
        bias[ni] = b[c];
        sc[ni]   = scale[c];
        of[ni]   = offset[c];
        attw[ni] = att[h * 64 + o * 32 + (c & 31)];
    }

#pragma unroll
    for (int mi = 0; mi < 4; ++mi) {
#pragma unroll
        for (int r = 0; r < 4; ++r) {
            int row = m_blk + mi * 16 + lhi * 4 + r;
            float v[4];
#pragma unroll
            for (int ni = 0; ni < 4; ++ni)
                v[ni] = fmaxf(acc[mi][ni][r] + bias[ni], 0.f);
#pragma unroll
            for (int p = 0; p < 2; ++p) {
                float x0 = v[2 * p], x1 = v[2 * p + 1];
                float s1 = x0 + x1;
                float s2 = x0 * x0 + x1 * x1;
                float sa = x0 * attw[2 * p] + x1 * attw[2 * p + 1];
#pragma unroll
                for (int off = 1; off < 16; off <<= 1) {
                    s1 += __shfl_xor(s1, off);
                    s2 += __shfl_xor(s2, off);
                    sa += __shfl_xor(sa, off);
                }
                float mean = s1 * (1.f / 32.f);
                float var  = s2 * (1.f / 32.f) - mean * mean;
                float rstd = rsqrtf(fmaxf(var, 0.f) + LN_EPS);
                float a_out = sa >= 0.f ? sa : 0.2f * sa;
                if (row < N_NODES) {
                    int hloc = (wid & 1) * 2 + p;
                    if (o == 0) {
#pragma unroll
                        for (int q = 0; q < 2; ++q) {
                            int ni = 2 * p + q;
                            int c = wid * 64 + ni * 16 + l15;
                            out[(size_t)row * COUT + c] =
                                (v[ni] - mean) * rstd * sc[ni] + of[ni];
                        }
                        if (l15 == 0) att_s[hloc * N_NODES + row] = a_out;
                    } else {
#pragma unroll
                        for (int q = 0; q < 2; ++q) {
                            int ni = 2 * p + q;
                            int c = wid * 64 + ni * 16 + l15 - 128;
                            feat_nei[(size_t)row * 128 + c] = f2bf(v[ni]);
                        }
                        if (l15 == 0) att_n[hloc * N_NODES + row] = a_out;
                    }
                }
            }
        }
    }
}

// ---------------------------------------------------------------------------
// CSR build step 1: histogram of rows.
// ---------------------------------------------------------------------------
__global__ __launch_bounds__(256) void hist_kernel(const int* __restrict__ row,
                                                   int* __restrict__ cnt) {
    int e = blockIdx.x * 256 + threadIdx.x;
    atomicAdd(&cnt[row[e]], 1);
}

// ---------------------------------------------------------------------------
// Hierarchical scan (3 kernels): per-block sums -> scan sums -> final.
// ---------------------------------------------------------------------------
__global__ __launch_bounds__(256) void scan1_kernel(const int* __restrict__ cnt,
                                                    int* __restrict__ bsum) {
    int i = blockIdx.x * 256 + threadIdx.x;
    int v = (i < N_NODES) ? cnt[i] : 0;
#pragma unroll
    for (int off = 1; off < 64; off <<= 1) v += __shfl_xor(v, off);
    __shared__ int s[4];
    if ((threadIdx.x & 63) == 0) s[threadIdx.x >> 6] = v;
    __syncthreads();
    if (threadIdx.x == 0) bsum[blockIdx.x] = s[0] + s[1] + s[2] + s[3];
}

__global__ __launch_bounds__(512) void scan2_kernel(const int* __restrict__ bsum,
                                                    int* __restrict__ boff) {
    __shared__ int s[512];
    int t = threadIdx.x;
    int v = (t < NB) ? bsum[t] : 0;
    s[t] = v;
    __syncthreads();
#pragma unroll
    for (int off = 1; off < 512; off <<= 1) {
        int u = (t >= off) ? s[t - off] : 0;
        __syncthreads();
        s[t] += u;
        __syncthreads();
    }
    if (t < NB) boff[t] = s[t] - v;   // exclusive prefix
}

__global__ __launch_bounds__(256) void scan3_kernel(const int* __restrict__ cnt,
                                                    const int* __restrict__ boff,
                                                    int* __restrict__ start,
                                                    int* __restrict__ pos) {
    __shared__ int s[256];
    int t = threadIdx.x;
    int i = blockIdx.x * 256 + t;
    int v = (i < N_NODES) ? cnt[i] : 0;
    s[t] = v;
    __syncthreads();
#pragma unroll
    for (int off = 1; off < 256; off <<= 1) {
        int u = (t >= off) ? s[t - off] : 0;
        __syncthreads();
        s[t] += u;
        __syncthreads();
    }
    if (i < N_NODES) {
        int e = boff[blockIdx.x] + s[t] - v;   // global exclusive prefix
        start[i] = e;
        pos[i]   = e;
    }
}

// ---------------------------------------------------------------------------
// CSR build step 3: scatter edges into row segments as int2{col, adj_bits}.
// ---------------------------------------------------------------------------
__global__ __launch_bounds__(256) void scatter_kernel(
    const int* __restrict__ row, const int* __restrict__ col,
    const float* __restrict__ adj, int* __restrict__ pos,
    int2* __restrict__ eca) {
    int e = blockIdx.x * 256 + threadIdx.x;
    int r = row[e];
    int slot = atomicAdd(&pos[r], 1);
    eca[slot] = make_int2(col[e], __float_as_int(adj[e]));
}

// ---------------------------------------------------------------------------
// Gather: one wave per node; lane l -> channels 2l,2l+1 (h = l>>4);
// feat_nei is bf16 (uint = 2 channels/lane); 2-edge software pipeline;
// fused LayerNorm -> out[:,128:256].
// ---------------------------------------------------------------------------
__global__ __launch_bounds__(256) void gather_kernel(
    const int* __restrict__ start, const int* __restrict__ cnt,
    const int2* __restrict__ eca,
    const float* __restrict__ att_s, const float* __restrict__ att_n,
    const ushort* __restrict__ feat_nei,
    const float* __restrict__ scale, const float* __restrict__ offset,
    float* __restrict__ out)
{
    int w = threadIdx.x >> 6;
    int l = threadIdx.x & 63;
    int n = blockIdx.x * 4 + w;
    if (n >= N_NODES) return;
    int h  = l >> 4;
    int c2 = l * 2;
    float a_s = att_s[h * N_NODES + n];
    const float* attn_h = att_n + h * N_NODES;
    int s0 = start[n], d = cnt[n];
    float ax = 0.f, ay = 0.f;

    int i = 0;
    for (; i + 2 <= d; i += 2) {
        int2 p0 = eca[s0 + i];
        int2 p1 = eca[s0 + i + 1];
        uint f0 = *(const uint*)&feat_nei[(size_t)p0.x * 128 + c2];
        uint f1 = *(const uint*)&feat_nei[(size_t)p1.x * 128 + c2];
        float w0 = (a_s + attn_h[p0.x]) * __int_as_float(p0.y);
        float w1 = (a_s + attn_h[p1.x]) * __int_as_float(p1.y);
        union { uint u; float f; } lo0, hi0, lo1, hi1;
        lo0.u = f0 << 16;         hi0.u = f0 & 0xffff0000u;
        lo1.u = f1 << 16;         hi1.u = f1 & 0xffff0000u;
        ax = fmaf(w0, lo0.f, ax); ay = fmaf(w0, hi0.f, ay);
        ax = fmaf(w1, lo1.f, ax); ay = fmaf(w1, hi1.f, ay);
    }
    if (i < d) {
        int2 p0 = eca[s0 + i];
        uint f0 = *(const uint*)&feat_nei[(size_t)p0.x * 128 + c2];
        float w0 = (a_s + attn_h[p0.x]) * __int_as_float(p0.y);
        union { uint u; float f; } lo0, hi0;
        lo0.u = f0 << 16;         hi0.u = f0 & 0xffff0000u;
        ax = fmaf(w0, lo0.f, ax); ay = fmaf(w0, hi0.f, ay);
    }

    float s1 = ax + ay, s2 = ax * ax + ay * ay;
#pragma unroll
    for (int off = 1; off < 16; off <<= 1) {
        s1 += __shfl_xor(s1, off);
        s2 += __shfl_xor(s2, off);
    }
    float mean = s1 * (1.f / 32.f);
    float var  = s2 * (1.f / 32.f) - mean * mean;
    float rstd = rsqrtf(fmaxf(var, 0.f) + LN_EPS);
    int ci = 128 + c2;
    float2 o2;
    o2.x = (ax - mean) * rstd * scale[ci]     + offset[ci];
    o2.y = (ay - mean) * rstd * scale[ci + 1] + offset[ci + 1];
    *(float2*)&out[n * COUT + ci] = o2;
}

// ---------------------------------------------------------------------------
extern "C" void kernel_launch(void* const* d_in, const int* in_sizes, int n_in,
                              void* d_out, int out_size, void* d_ws, size_t ws_size,
                              hipStream_t stream)
{
    const float* feat_in = (const float*)d_in[0];
    const int*   row     = (const int*)d_in[1];
    const int*   col     = (const int*)d_in[2];
    const float* adj     = (const float*)d_in[3];
    const float* W       = (const float*)d_in[4];
    const float* b       = (const float*)d_in[5];
    const float* att     = (const float*)d_in[6];
    const float* scale   = (const float*)d_in[7];
    const float* offset  = (const float*)d_in[8];
    float* out = (float*)d_out;

    float*  ws       = (float*)d_ws;
    ushort* Wn_hi    = (ushort*)ws;                  // 65536 ushort
    ushort* Wn_lo    = Wn_hi + 65536;                // 65536 ushort
    float*  att_s    = ws + 65536;
    float*  att_n    = att_s + NH * N_NODES;
    ushort* feat_b   = (ushort*)(att_n + NH * N_NODES);   // N*128 ushort (25.6MB)
    int*    cnt      = (int*)(feat_b + (size_t)N_NODES * 128);
    int*    startp   = cnt + N_NODES;
    int*    pos      = startp + N_NODES;
    int*    bsum     = pos + N_NODES;                // 392
    int*    boff     = bsum + 392;                   // 392
    int2*   eca      = (int2*)(boff + 392);          // 8B aligned

    hipMemsetAsync(cnt, 0, N_NODES * sizeof(int), stream);
    wn_kernel<<<256, 256, 0, stream>>>(W, Wn_hi, Wn_lo);
    gemm_kernel<<<(N_NODES + BM - 1) / BM, 256, 0, stream>>>(
        feat_in, Wn_hi, Wn_lo, b, att, scale, offset, out, feat_b, att_s, att_n);
    hist_kernel<<<E_EDGES / 256, 256, 0, stream>>>(row, cnt);
    scan1_kernel<<<NB, 256, 0, stream>>>(cnt, bsum);
    scan2_kernel<<<1, 512, 0, stream>>>(bsum, boff);
    scan3_kernel<<<NB, 256, 0, stream>>>(cnt, boff, startp, pos);
    scatter_kernel<<<E_EDGES / 256, 256, 0, stream>>>(row, col, adj, pos, eca);
    gather_kernel<<<(N_NODES + 3) / 4, 256, 0, stream>>>(startp, cnt, eca, att_s,
                                                         att_n, feat_b, scale,
                                                         offset, out);
}

// Round 10
// 535.648 us; speedup vs baseline: 6.1729x; 1.0619x over previous
//
#include <hip/hip_runtime.h>

#define N_NODES 100000
#define E_EDGES 1600000
#define DIN 256
#define NH 4
#define DH 32
#define COUT 256
#define LN_EPS 1e-9f
#define BM 64
#define BK 32
#define KPAD (BK + 8)
#define NB 391   // ceil(N_NODES / 256)

typedef __attribute__((ext_vector_type(4))) float     f32x4;
typedef __attribute__((ext_vector_type(8))) _Float16  f16x8;
typedef __attribute__((ext_vector_type(8))) ushort    u16x8;

__device__ __forceinline__ ushort f2bf(float x) {
    union { float f; uint u; } v; v.f = x;
    uint r = v.u + 0x7fffu + ((v.u >> 16) & 1u);
    return (ushort)(r >> 16);
}

// ---------------------------------------------------------------------------
// W (2,4,256,32) f32 -> Wn[c][k] fp16 (N x K, row-major), c = o*128+h*32+q
// ---------------------------------------------------------------------------
__global__ __launch_bounds__(256) void wn_kernel(const float* __restrict__ W,
                                                 _Float16* __restrict__ Wn) {
    int i = blockIdx.x * 256 + threadIdx.x;   // 65536
    int c = i >> 8, k = i & 255;
    int o = c >> 7, h = (c >> 5) & 3, q = c & 31;
    Wn[i] = (_Float16)W[((o * NH + h) * DIN + k) * DH + q];
}

// ---------------------------------------------------------------------------
// FP16 MFMA GEMM: block = 64 rows x 256 cols, K=256 in 8 steps of 32.
// Single plane (fp16 rel err 2^-12 -> passes threshold, per R4 calibration).
// Fused epilogue: ReLU + per-head LN / att logits; feat_nei stored bf16.
// ---------------------------------------------------------------------------
__global__ __launch_bounds__(256) void gemm_kernel(
    const float* __restrict__ feat_in, const _Float16* __restrict__ Wn,
    const float* __restrict__ b, const float* __restrict__ att,
    const float* __restrict__ scale, const float* __restrict__ offset,
    float* __restrict__ out, ushort* __restrict__ feat_nei,
    float* __restrict__ att_s, float* __restrict__ att_n)
{
    __shared__ _Float16 sA[BM][KPAD];    // 5 KB
    __shared__ _Float16 sB[256][KPAD];   // 20 KB

    const int t   = threadIdx.x;
    const int wid = t >> 6;
    const int l   = t & 63;
    const int l15 = l & 15;
    const int lhi = l >> 4;
    const int m_blk = blockIdx.x * BM;

    f32x4 acc[4][4] = {};

    // A staging: thread -> (row = t>>2, k-octet = t&3), 8 f32 -> 8 fp16
    const int arow = t >> 2;
    const int akq  = t & 3;
    const int arow_g = min(m_blk + arow, N_NODES - 1);
    const float* aptr = feat_in + (size_t)arow_g * DIN + akq * 8;

    for (int kc = 0; kc < DIN; kc += BK) {
        float4 f0 = *(const float4*)(aptr + kc);
        float4 f1 = *(const float4*)(aptr + kc + 4);
        f16x8 ph = { (_Float16)f0.x, (_Float16)f0.y, (_Float16)f0.z,
                     (_Float16)f0.w, (_Float16)f1.x, (_Float16)f1.y,
                     (_Float16)f1.z, (_Float16)f1.w };
        *(f16x8*)&sA[arow][akq * 8] = ph;

        // B staging: 256 rows x 32 k = 1024 chunks of 8 fp16; 4 iters
#pragma unroll
        for (int i = 0; i < 4; ++i) {
            int c = i * 256 + t;
            int rrow = c >> 2, koff = (c & 3) * 8;
            *(f16x8*)&sB[rrow][koff] =
                *(const f16x8*)(Wn + rrow * 256 + kc + koff);
        }
        __syncthreads();

        f16x8 a[4], bb[4];
#pragma unroll
        for (int mi = 0; mi < 4; ++mi)
            a[mi] = *(f16x8*)&sA[mi * 16 + l15][lhi * 8];
#pragma unroll
        for (int ni = 0; ni < 4; ++ni)
            bb[ni] = *(f16x8*)&sB[wid * 64 + ni * 16 + l15][lhi * 8];
#pragma unroll
        for (int mi = 0; mi < 4; ++mi)
#pragma unroll
            for (int ni = 0; ni < 4; ++ni)
                acc[mi][ni] = __builtin_amdgcn_mfma_f32_16x16x32_f16(
                    a[mi], bb[ni], acc[mi][ni], 0, 0, 0);
        __syncthreads();
    }

    // ---- epilogue ----
    const int o = wid >> 1;
    float bias[4], attw[4], sc[4], of[4];
#pragma unroll
    for (int ni = 0; ni < 4; ++ni) {
        int c = wid * 64 + ni * 16 + l15;
        int h = (c >> 5) & 3;
        bias[ni] = b[c];
        sc[ni]   = scale[c];
        of[ni]   = offset[c];
        attw[ni] = att[h * 64 + o * 32 + (c & 31)];
    }

#pragma unroll
    for (int mi = 0; mi < 4; ++mi) {
#pragma unroll
        for (int r = 0; r < 4; ++r) {
            int row = m_blk + mi * 16 + lhi * 4 + r;
            float v[4];
#pragma unroll
            for (int ni = 0; ni < 4; ++ni)
                v[ni] = fmaxf(acc[mi][ni][r] + bias[ni], 0.f);
#pragma unroll
            for (int p = 0; p < 2; ++p) {
                float x0 = v[2 * p], x1 = v[2 * p + 1];
                float s1 = x0 + x1;
                float s2 = x0 * x0 + x1 * x1;
                float sa = x0 * attw[2 * p] + x1 * attw[2 * p + 1];
#pragma unroll
                for (int off = 1; off < 16; off <<= 1) {
                    s1 += __shfl_xor(s1, off);
                    s2 += __shfl_xor(s2, off);
                    sa += __shfl_xor(sa, off);
                }
                float mean = s1 * (1.f / 32.f);
                float var  = s2 * (1.f / 32.f) - mean * mean;
                float rstd = rsqrtf(fmaxf(var, 0.f) + LN_EPS);
                float a_out = sa >= 0.f ? sa : 0.2f * sa;
                if (row < N_NODES) {
                    int hloc = (wid & 1) * 2 + p;
                    if (o == 0) {
#pragma unroll
                        for (int q = 0; q < 2; ++q) {
                            int ni = 2 * p + q;
                            int c = wid * 64 + ni * 16 + l15;
                            out[(size_t)row * COUT + c] =
                                (v[ni] - mean) * rstd * sc[ni] + of[ni];
                        }
                        if (l15 == 0) att_s[hloc * N_NODES + row] = a_out;
                    } else {
#pragma unroll
                        for (int q = 0; q < 2; ++q) {
                            int ni = 2 * p + q;
                            int c = wid * 64 + ni * 16 + l15 - 128;
                            feat_nei[(size_t)row * 128 + c] = f2bf(v[ni]);
                        }
                        if (l15 == 0) att_n[hloc * N_NODES + row] = a_out;
                    }
                }
            }
        }
    }
}

// ---------------------------------------------------------------------------
// CSR build step 1: histogram of rows.
// ---------------------------------------------------------------------------
__global__ __launch_bounds__(256) void hist_kernel(const int* __restrict__ row,
                                                   int* __restrict__ cnt) {
    int e = blockIdx.x * 256 + threadIdx.x;
    atomicAdd(&cnt[row[e]], 1);
}

// ---------------------------------------------------------------------------
// Hierarchical scan (3 kernels): per-block sums -> scan sums -> final.
// ---------------------------------------------------------------------------
__global__ __launch_bounds__(256) void scan1_kernel(const int* __restrict__ cnt,
                                                    int* __restrict__ bsum) {
    int i = blockIdx.x * 256 + threadIdx.x;
    int v = (i < N_NODES) ? cnt[i] : 0;
#pragma unroll
    for (int off = 1; off < 64; off <<= 1) v += __shfl_xor(v, off);
    __shared__ int s[4];
    if ((threadIdx.x & 63) == 0) s[threadIdx.x >> 6] = v;
    __syncthreads();
    if (threadIdx.x == 0) bsum[blockIdx.x] = s[0] + s[1] + s[2] + s[3];
}

__global__ __launch_bounds__(512) void scan2_kernel(const int* __restrict__ bsum,
                                                    int* __restrict__ boff) {
    __shared__ int s[512];
    int t = threadIdx.x;
    int v = (t < NB) ? bsum[t] : 0;
    s[t] = v;
    __syncthreads();
#pragma unroll
    for (int off = 1; off < 512; off <<= 1) {
        int u = (t >= off) ? s[t - off] : 0;
        __syncthreads();
        s[t] += u;
        __syncthreads();
    }
    if (t < NB) boff[t] = s[t] - v;   // exclusive prefix
}

__global__ __launch_bounds__(256) void scan3_kernel(const int* __restrict__ cnt,
                                                    const int* __restrict__ boff,
                                                    int* __restrict__ start,
                                                    int* __restrict__ pos) {
    __shared__ int s[256];
    int t = threadIdx.x;
    int i = blockIdx.x * 256 + t;
    int v = (i < N_NODES) ? cnt[i] : 0;
    s[t] = v;
    __syncthreads();
#pragma unroll
    for (int off = 1; off < 256; off <<= 1) {
        int u = (t >= off) ? s[t - off] : 0;
        __syncthreads();
        s[t] += u;
        __syncthreads();
    }
    if (i < N_NODES) {
        int e = boff[blockIdx.x] + s[t] - v;   // global exclusive prefix
        start[i] = e;
        pos[i]   = e;
    }
}

// ---------------------------------------------------------------------------
// CSR build step 3: scatter edges into row segments as int2{col, adj_bits}.
// ---------------------------------------------------------------------------
__global__ __launch_bounds__(256) void scatter_kernel(
    const int* __restrict__ row, const int* __restrict__ col,
    const float* __restrict__ adj, int* __restrict__ pos,
    int2* __restrict__ eca) {
    int e = blockIdx.x * 256 + threadIdx.x;
    int r = row[e];
    int slot = atomicAdd(&pos[r], 1);
    eca[slot] = make_int2(col[e], __float_as_int(adj[e]));
}

// ---------------------------------------------------------------------------
// Gather: one wave per node; lane l -> channels 2l,2l+1 (h = l>>4);
// feat_nei bf16 (uint = 2 channels/lane); 2-edge pipeline; fused LN.
// ---------------------------------------------------------------------------
__global__ __launch_bounds__(256) void gather_kernel(
    const int* __restrict__ start, const int* __restrict__ cnt,
    const int2* __restrict__ eca,
    const float* __restrict__ att_s, const float* __restrict__ att_n,
    const ushort* __restrict__ feat_nei,
    const float* __restrict__ scale, const float* __restrict__ offset,
    float* __restrict__ out)
{
    int w = threadIdx.x >> 6;
    int l = threadIdx.x & 63;
    int n = blockIdx.x * 4 + w;
    if (n >= N_NODES) return;
    int h  = l >> 4;
    int c2 = l * 2;
    float a_s = att_s[h * N_NODES + n];
    const float* attn_h = att_n + h * N_NODES;
    int s0 = start[n], d = cnt[n];
    float ax = 0.f, ay = 0.f;

    int i = 0;
    for (; i + 2 <= d; i += 2) {
        int2 p0 = eca[s0 + i];
        int2 p1 = eca[s0 + i + 1];
        uint f0 = *(const uint*)&feat_nei[(size_t)p0.x * 128 + c2];
        uint f1 = *(const uint*)&feat_nei[(size_t)p1.x * 128 + c2];
        float w0 = (a_s + attn_h[p0.x]) * __int_as_float(p0.y);
        float w1 = (a_s + attn_h[p1.x]) * __int_as_float(p1.y);
        union { uint u; float f; } lo0, hi0, lo1, hi1;
        lo0.u = f0 << 16;         hi0.u = f0 & 0xffff0000u;
        lo1.u = f1 << 16;         hi1.u = f1 & 0xffff0000u;
        ax = fmaf(w0, lo0.f, ax); ay = fmaf(w0, hi0.f, ay);
        ax = fmaf(w1, lo1.f, ax); ay = fmaf(w1, hi1.f, ay);
    }
    if (i < d) {
        int2 p0 = eca[s0 + i];
        uint f0 = *(const uint*)&feat_nei[(size_t)p0.x * 128 + c2];
        float w0 = (a_s + attn_h[p0.x]) * __int_as_float(p0.y);
        union { uint u; float f; } lo0, hi0;
        lo0.u = f0 << 16;         hi0.u = f0 & 0xffff0000u;
        ax = fmaf(w0, lo0.f, ax); ay = fmaf(w0, hi0.f, ay);
    }

    float s1 = ax + ay, s2 = ax * ax + ay * ay;
#pragma unroll
    for (int off = 1; off < 16; off <<= 1) {
        s1 += __shfl_xor(s1, off);
        s2 += __shfl_xor(s2, off);
    }
    float mean = s1 * (1.f / 32.f);
    float var  = s2 * (1.f / 32.f) - mean * mean;
    float rstd = rsqrtf(fmaxf(var, 0.f) + LN_EPS);
    int ci = 128 + c2;
    float2 o2;
    o2.x = (ax - mean) * rstd * scale[ci]     + offset[ci];
    o2.y = (ay - mean) * rstd * scale[ci + 1] + offset[ci + 1];
    *(float2*)&out[n * COUT + ci] = o2;
}

// ---------------------------------------------------------------------------
extern "C" void kernel_launch(void* const* d_in, const int* in_sizes, int n_in,
                              void* d_out, int out_size, void* d_ws, size_t ws_size,
                              hipStream_t stream)
{
    const float* feat_in = (const float*)d_in[0];
    const int*   row     = (const int*)d_in[1];
    const int*   col     = (const int*)d_in[2];
    const float* adj     = (const float*)d_in[3];
    const float* W       = (const float*)d_in[4];
    const float* b       = (const float*)d_in[5];
    const float* att     = (const float*)d_in[6];
    const float* scale   = (const float*)d_in[7];
    const float* offset  = (const float*)d_in[8];
    float* out = (float*)d_out;

    float*     ws       = (float*)d_ws;
    _Float16*  Wn       = (_Float16*)ws;             // 65536 fp16 = 32768 f32
    float*     att_s    = ws + 32768;
    float*     att_n    = att_s + NH * N_NODES;
    ushort*    feat_b   = (ushort*)(att_n + NH * N_NODES);  // N*128 bf16
    int*       cnt      = (int*)(feat_b + (size_t)N_NODES * 128);
    int*       startp   = cnt + N_NODES;
    int*       pos      = startp + N_NODES;
    int*       bsum     = pos + N_NODES;             // 392
    int*       boff     = bsum + 392;                // 392
    int2*      eca      = (int2*)(boff + 392);       // 8B aligned

    hipMemsetAsync(cnt, 0, N_NODES * sizeof(int), stream);
    wn_kernel<<<256, 256, 0, stream>>>(W, Wn);
    gemm_kernel<<<(N_NODES + BM - 1) / BM, 256, 0, stream>>>(
        feat_in, Wn, b, att, scale, offset, out, feat_b, att_s, att_n);
    hist_kernel<<<E_EDGES / 256, 256, 0, stream>>>(row, cnt);
    scan1_kernel<<<NB, 256, 0, stream>>>(cnt, bsum);
    scan2_kernel<<<1, 512, 0, stream>>>(bsum, boff);
    scan3_kernel<<<NB, 256, 0, stream>>>(cnt, boff, startp, pos);
    scatter_kernel<<<E_EDGES / 256, 256, 0, stream>>>(row, col, adj, pos, eca);
    gather_kernel<<<(N_NODES + 3) / 4, 256, 0, stream>>>(startp, cnt, eca, att_s,
                                                         att_n, feat_b, scale,
                                                         offset, out);
}